// Round 17
// baseline (55.627 us; speedup 1.0000x reference)
//
#include <hip/hip_runtime.h>
#include <math.h>

// Chamfer distance via MFMA, B=8, N=8192, fp32 in, fp32 scalar out.
//
// d(q,t) = |q|^2 + |t|^2 - 2 q.t  ==  dot(A_row(q), B_col(t)) with K=5:
//   A_row = (-2x_q, -2y_q, -2z_q, 1, |q|^2),  B_col = (x_t, y_t, z_t, |t|^2, 1)
// in f16 (zero-padded to K=16).  One v_mfma_f32_32x32x16_f16 -> a 32x32 tile
// of complete squared distances in fp32.
//
// R16: double-buffered DMA staging (global_load_lds, T3 2-phase): issue
// chunk t+1's DMA before computing chunk t -> staging latency hides under
// the 16-iter compute phase; no VGPR round-trip, no staging address VALU.
//
// prep:   clouds -> packed f16 form (x,y,z,n,1,0,0,0); zero sum counter.
// main:   512 blocks = dir(2) x batch(8) x rowblock(32); 4 waves x 2 strips
//         = 256 rows/block, all 8192 cols -> rowmins block-final; epilogue
//         does sqrt + block-sum + ONE u64 fixed-point atomicAdd per block
//         (order-independent => deterministic).  u32 min fold (squared
//         dists are uint-monotone; fuses to v_min3_u32 -- no NaN blocker).
// final:  1 thread: out = counter / 2^26 / TOTALQ.

#define NPTS   8192
#define NB     8
#define NPC    (NB * NPTS)         // 65536
#define BLOCK  256
#define CHUNK  1024
#define NCH    (NPTS / CHUNK)      // 8 chunks
#define TOTALQ (2 * NPC)           // 131072
#define EPSV   1e-12f
#define FXSCALE 67108864.0         // 2^26

typedef _Float16 v8h  __attribute__((ext_vector_type(8)));
typedef float    v16f __attribute__((ext_vector_type(16)));

__global__ __launch_bounds__(256) void chamfer_prep(
    const float* __restrict__ xyz1, const float* __restrict__ xyz2,
    v8h* __restrict__ form, unsigned long long* __restrict__ counter)
{
    const int gid = blockIdx.x * 256 + threadIdx.x;      // [0, TOTALQ)
    if (gid == 0) counter[0] = 0ULL;
    const float* __restrict__ src = (gid < NPC) ? xyz1 : xyz2;
    const int i = (gid < NPC) ? gid : gid - NPC;
    float x = src[3 * i], y = src[3 * i + 1], z = src[3 * i + 2];
    _Float16 xh = (_Float16)x, yh = (_Float16)y, zh = (_Float16)z;
    float xf = (float)xh, yf = (float)yh, zf = (float)zh;
    float n = fmaf(xf, xf, fmaf(yf, yf, zf * zf));
    v8h bv = {};
    bv[0] = xh; bv[1] = yh; bv[2] = zh;
    bv[3] = (_Float16)n; bv[4] = (_Float16)1.0f;
    form[gid] = bv;
}

#define MFMA(va, vb) __builtin_amdgcn_mfma_f32_32x32x16_f16((va), (vb), vzero, 0, 0, 0)

__device__ __forceinline__ unsigned umin2(unsigned a, unsigned b) {
    return a < b ? a : b;
}

__global__ __launch_bounds__(BLOCK, 4) void chamfer_mfma_min(
    const v8h* __restrict__ form, unsigned long long* __restrict__ counter)
{
    const int bid = blockIdx.x;             // [0, 512)
    const int rb  = bid & 31;
    const int b   = (bid >> 5) & 7;
    const int dir = (bid >> 8) & 1;

    const v8h* __restrict__ qf = form + (size_t)dir * NPC + (size_t)b * NPTS;
    const v8h* __restrict__ tf = form + (size_t)(1 - dir) * NPC + (size_t)b * NPTS;

    const int tid  = threadIdx.x;
    const int lane = tid & 63;
    const int w    = tid >> 6;              // wave 0..3, two 32-row strips each
    const int c31  = lane & 31;
    const int rowbase = rb * 256;

    __shared__ v8h bsh[2][CHUNK];           // 2 x 16 KB double buffer

    // DMA stage chunk `ch` into buffer `nb`: per wave, LDS dest is linear
    // (base + lane*16) as global_load_lds requires; global src is per-lane.
#define STAGE(nb, ch)                                                        \
    {                                                                        \
        const v8h* gsrc = tf + (ch) * CHUNK;                                 \
        _Pragma("unroll")                                                    \
        for (int k = 0; k < CHUNK / BLOCK; ++k)                              \
            __builtin_amdgcn_global_load_lds(                                \
                (const __attribute__((address_space(1))) unsigned*)          \
                    (gsrc + k * BLOCK + tid),                                \
                (__attribute__((address_space(3))) unsigned*)                \
                    (&bsh[nb][k * BLOCK + tid]),                             \
                16, 0, 0);                                                   \
    }

    // A fragments: lanes<32 carry k=0..7 (5 live slots); lanes>=32 carry
    // k=8..15 which are all zero.
    v8h a0 = {}, a1 = {};
    if (lane < 32) {
        const _Float16 m2 = (_Float16)(-2.0f);
        v8h f = qf[rowbase + w * 64 + lane];
        a0[0] = m2 * f[0]; a0[1] = m2 * f[1]; a0[2] = m2 * f[2];
        a0[3] = (_Float16)1.0f; a0[4] = f[3];
        f = qf[rowbase + w * 64 + 32 + lane];
        a1[0] = m2 * f[0]; a1[1] = m2 * f[1]; a1[2] = m2 * f[2];
        a1[3] = (_Float16)1.0f; a1[4] = f[3];
    }

    unsigned rm0[16], rm1[16];
#pragma unroll
    for (int r = 0; r < 16; ++r) { rm0[r] = 0x7F7F7F7FU; rm1[r] = 0x7F7F7F7FU; }

    const v16f vzero = {};

    STAGE(0, 0);
    asm volatile("s_waitcnt vmcnt(0)" ::: "memory");
    __syncthreads();

    for (int ch = 0; ch < NCH; ++ch) {
        const int cur = ch & 1;
        if (ch + 1 < NCH) STAGE(cur ^ 1, ch + 1);    // DMA next under compute

#pragma unroll
        for (int cc = 0; cc < CHUNK / 64; ++cc) {
            const v8h b0 = bsh[cur][cc * 64 + c31];  // broadcast b128
            const v8h b1 = bsh[cur][cc * 64 + 32 + c31];
            v16f p0 = MFMA(a0, b0);
            v16f q0 = MFMA(a0, b1);
            v16f p1 = MFMA(a1, b0);
            v16f q1 = MFMA(a1, b1);
#pragma unroll
            for (int r = 0; r < 16; ++r)
                rm0[r] = umin2(rm0[r], umin2(__builtin_bit_cast(unsigned, p0[r]),
                                             __builtin_bit_cast(unsigned, q0[r])));
#pragma unroll
            for (int r = 0; r < 16; ++r)
                rm1[r] = umin2(rm1[r], umin2(__builtin_bit_cast(unsigned, p1[r]),
                                             __builtin_bit_cast(unsigned, q1[r])));
        }

        asm volatile("s_waitcnt vmcnt(0)" ::: "memory");  // next DMA landed
        __syncthreads();                                  // all waves done
    }

    // Epilogue: butterfly row-min across the 32 lanes sharing each row
    // (rowmins are FINAL: this block saw all 8192 cols), sqrt, block-sum,
    // one u64 fixed-point atomicAdd (order-independent => deterministic).
    float acc = 0.0f;
#pragma unroll
    for (int s = 0; s < 2; ++s) {
#pragma unroll
        for (int r = 0; r < 16; ++r) {
            unsigned u = s ? rm1[r] : rm0[r];
            u = umin2(u, __shfl_xor(u, 1));
            u = umin2(u, __shfl_xor(u, 2));
            u = umin2(u, __shfl_xor(u, 4));
            u = umin2(u, __shfl_xor(u, 8));
            u = umin2(u, __shfl_xor(u, 16));
            if ((lane & 31) == 0) {
                float v = __builtin_bit_cast(float, u);
                acc += sqrtf(fmaxf(fmaxf(v, 0.0f), EPSV));
            }
        }
    }
    acc += __shfl_xor(acc, 32);             // lane 0: this wave's 64 rows

    __syncthreads();                        // safe to reuse bsh
    float* red = (float*)bsh;
    if (lane == 0) red[w] = acc;
    __syncthreads();
    if (tid == 0) {
        float s = red[0] + red[1] + red[2] + red[3];
        unsigned long long fx = (unsigned long long)((double)s * FXSCALE + 0.5);
        atomicAdd(counter, fx);
    }
}

__global__ void chamfer_finalize(
    const unsigned long long* __restrict__ counter, float* __restrict__ out)
{
    out[0] = (float)((double)counter[0] * (1.0 / FXSCALE) / (double)TOTALQ);
}

extern "C" void kernel_launch(void* const* d_in, const int* in_sizes, int n_in,
                              void* d_out, int out_size, void* d_ws, size_t ws_size,
                              hipStream_t stream) {
    const float* xyz1 = (const float*)d_in[0];
    const float* xyz2 = (const float*)d_in[1];
    float* out = (float*)d_out;

    v8h* formbuf = (v8h*)d_ws;                                   // TOTALQ v8h = 2 MB
    unsigned long long* counter = (unsigned long long*)(formbuf + TOTALQ);

    chamfer_prep<<<TOTALQ / 256, 256, 0, stream>>>(xyz1, xyz2, formbuf, counter);
    chamfer_mfma_min<<<2 * NB * 32, BLOCK, 0, stream>>>(formbuf, counter);
    chamfer_finalize<<<1, 1, 0, stream>>>(counter, out);
}

// Round 18
// 51.564 us; speedup vs baseline: 1.0788x; 1.0788x over previous
//
#include <hip/hip_runtime.h>
#include <math.h>

// Chamfer distance via MFMA, B=8, N=8192, fp32 in, fp32 scalar out.
//
// d(q,t) = |q|^2 + |t|^2 - 2 q.t  ==  dot(A_row(q), B_col(t)) with K=5:
//   A_row = (-2x_q, -2y_q, -2z_q, 1, |q|^2),  B_col = (x_t, y_t, z_t, |t|^2, 1)
// in f16 (zero-padded to K=16).  One v_mfma_f32_32x32x16_f16 -> a 32x32 tile
// of complete squared distances in fp32.
//
// R17: NO LDS staging (guide common-mistake #7: don't stage what the cache
// already holds).  The B-slab is 128 KB/block and 16 blocks/batch read the
// SAME cloud -> L1/L2-resident.  B-fragments load straight from global
// (L1 broadcast, deep vmem pipelining, zero barriers in the main loop);
// kills the ds_read->MFMA 120-cyc chain, staging writes, and chunk drains.
//
// prep:   clouds -> packed f16 form (x,y,z,n,1,0,0,0); zero sum counter.
// main:   512 blocks = dir(2) x batch(8) x rowblock(32); 4 waves x 2 strips
//         = 256 rows/block, all 8192 cols -> rowmins block-final; epilogue
//         does sqrt + block-sum + ONE u64 fixed-point atomicAdd per block
//         (order-independent => deterministic).  u32 min fold (squared
//         dists are uint-monotone; fuses to v_min3_u32).
// final:  1 thread: out = counter / 2^26 / TOTALQ.

#define NPTS   8192
#define NB     8
#define NPC    (NB * NPTS)         // 65536
#define BLOCK  256
#define TOTALQ (2 * NPC)           // 131072
#define EPSV   1e-12f
#define FXSCALE 67108864.0         // 2^26

typedef _Float16 v8h  __attribute__((ext_vector_type(8)));
typedef float    v16f __attribute__((ext_vector_type(16)));

__global__ __launch_bounds__(256) void chamfer_prep(
    const float* __restrict__ xyz1, const float* __restrict__ xyz2,
    v8h* __restrict__ form, unsigned long long* __restrict__ counter)
{
    const int gid = blockIdx.x * 256 + threadIdx.x;      // [0, TOTALQ)
    if (gid == 0) counter[0] = 0ULL;
    const float* __restrict__ src = (gid < NPC) ? xyz1 : xyz2;
    const int i = (gid < NPC) ? gid : gid - NPC;
    float x = src[3 * i], y = src[3 * i + 1], z = src[3 * i + 2];
    _Float16 xh = (_Float16)x, yh = (_Float16)y, zh = (_Float16)z;
    float xf = (float)xh, yf = (float)yh, zf = (float)zh;
    float n = fmaf(xf, xf, fmaf(yf, yf, zf * zf));
    v8h bv = {};
    bv[0] = xh; bv[1] = yh; bv[2] = zh;
    bv[3] = (_Float16)n; bv[4] = (_Float16)1.0f;
    form[gid] = bv;
}

#define MFMA(va, vb) __builtin_amdgcn_mfma_f32_32x32x16_f16((va), (vb), vzero, 0, 0, 0)

__device__ __forceinline__ unsigned umin2(unsigned a, unsigned b) {
    return a < b ? a : b;
}

__global__ __launch_bounds__(BLOCK, 4) void chamfer_mfma_min(
    const v8h* __restrict__ form, unsigned long long* __restrict__ counter)
{
    const int bid = blockIdx.x;             // [0, 512)
    const int rb  = bid & 31;
    const int b   = (bid >> 5) & 7;
    const int dir = (bid >> 8) & 1;

    const v8h* __restrict__ qf = form + (size_t)dir * NPC + (size_t)b * NPTS;
    const v8h* __restrict__ tf = form + (size_t)(1 - dir) * NPC + (size_t)b * NPTS;

    const int tid  = threadIdx.x;
    const int lane = tid & 63;
    const int w    = tid >> 6;              // wave 0..3, two 32-row strips each
    const int c31  = lane & 31;
    const int rowbase = rb * 256;

    // A fragments: lanes<32 carry k=0..7 (5 live slots); lanes>=32 carry
    // k=8..15 which are all zero.
    v8h a0 = {}, a1 = {};
    if (lane < 32) {
        const _Float16 m2 = (_Float16)(-2.0f);
        v8h f = qf[rowbase + w * 64 + lane];
        a0[0] = m2 * f[0]; a0[1] = m2 * f[1]; a0[2] = m2 * f[2];
        a0[3] = (_Float16)1.0f; a0[4] = f[3];
        f = qf[rowbase + w * 64 + 32 + lane];
        a1[0] = m2 * f[0]; a1[1] = m2 * f[1]; a1[2] = m2 * f[2];
        a1[3] = (_Float16)1.0f; a1[4] = f[3];
    }

    unsigned rm0[16], rm1[16];
#pragma unroll
    for (int r = 0; r < 16; ++r) { rm0[r] = 0x7F7F7F7FU; rm1[r] = 0x7F7F7F7FU; }

    const v16f vzero = {};
    const v8h* __restrict__ tcol = tf + c31;

    // B-fragments straight from global: L1-served (16 blocks/batch share
    // this cloud), no barriers -> compiler pipelines loads deep ahead.
#pragma unroll 4
    for (int cc = 0; cc < NPTS / 64; ++cc) {
        const v8h b0 = tcol[cc * 64];
        const v8h b1 = tcol[cc * 64 + 32];
        v16f p0 = MFMA(a0, b0);
        v16f q0 = MFMA(a0, b1);
        v16f p1 = MFMA(a1, b0);
        v16f q1 = MFMA(a1, b1);
#pragma unroll
        for (int r = 0; r < 16; ++r)
            rm0[r] = umin2(rm0[r], umin2(__builtin_bit_cast(unsigned, p0[r]),
                                         __builtin_bit_cast(unsigned, q0[r])));
#pragma unroll
        for (int r = 0; r < 16; ++r)
            rm1[r] = umin2(rm1[r], umin2(__builtin_bit_cast(unsigned, p1[r]),
                                         __builtin_bit_cast(unsigned, q1[r])));
    }

    // Epilogue: butterfly row-min across the 32 lanes sharing each row
    // (rowmins are FINAL: this block saw all 8192 cols), sqrt, block-sum,
    // one u64 fixed-point atomicAdd (order-independent => deterministic).
    float acc = 0.0f;
#pragma unroll
    for (int s = 0; s < 2; ++s) {
#pragma unroll
        for (int r = 0; r < 16; ++r) {
            unsigned u = s ? rm1[r] : rm0[r];
            u = umin2(u, __shfl_xor(u, 1));
            u = umin2(u, __shfl_xor(u, 2));
            u = umin2(u, __shfl_xor(u, 4));
            u = umin2(u, __shfl_xor(u, 8));
            u = umin2(u, __shfl_xor(u, 16));
            if ((lane & 31) == 0) {
                float v = __builtin_bit_cast(float, u);
                acc += sqrtf(fmaxf(fmaxf(v, 0.0f), EPSV));
            }
        }
    }
    acc += __shfl_xor(acc, 32);             // lane 0: this wave's 64 rows

    __shared__ float red[4];
    __syncthreads();
    if (lane == 0) red[w] = acc;
    __syncthreads();
    if (tid == 0) {
        float s = red[0] + red[1] + red[2] + red[3];
        unsigned long long fx = (unsigned long long)((double)s * FXSCALE + 0.5);
        atomicAdd(counter, fx);
    }
}

__global__ void chamfer_finalize(
    const unsigned long long* __restrict__ counter, float* __restrict__ out)
{
    out[0] = (float)((double)counter[0] * (1.0 / FXSCALE) / (double)TOTALQ);
}

extern "C" void kernel_launch(void* const* d_in, const int* in_sizes, int n_in,
                              void* d_out, int out_size, void* d_ws, size_t ws_size,
                              hipStream_t stream) {
    const float* xyz1 = (const float*)d_in[0];
    const float* xyz2 = (const float*)d_in[1];
    float* out = (float*)d_out;

    v8h* formbuf = (v8h*)d_ws;                                   // TOTALQ v8h = 2 MB
    unsigned long long* counter = (unsigned long long*)(formbuf + TOTALQ);

    chamfer_prep<<<TOTALQ / 256, 256, 0, stream>>>(xyz1, xyz2, formbuf, counter);
    chamfer_mfma_min<<<2 * NB * 32, BLOCK, 0, stream>>>(formbuf, counter);
    chamfer_finalize<<<1, 1, 0, stream>>>(counter, out);
}